// Round 1
// baseline (229.866 us; speedup 1.0000x reference)
//
#include <hip/hip_runtime.h>
#include <math.h>

#define NG 16
#define GW 128
#define NEGV -1.0e9f
#define EPSBN 1e-5f
#define MIN_SCORE 0.1f
#define TOLK 1e-7f

// ---------- helpers ----------
__device__ __forceinline__ unsigned encf(float f) {
  unsigned u = __float_as_uint(f);
  return (u & 0x80000000u) ? ~u : (u | 0x80000000u);
}
__device__ __forceinline__ float decf(unsigned u) {
  unsigned b = (u & 0x80000000u) ? (u & 0x7fffffffu) : ~u;
  return __uint_as_float(b);
}
__device__ __forceinline__ float eluf(float v) { return v > 0.0f ? v : expm1f(v); }

// ---------- kernels ----------
__global__ void k_init(const float* __restrict__ x, const float* __restrict__ gcn_w,
                       float* __restrict__ deg, float* __restrict__ agg,
                       float* __restrict__ xw, unsigned* __restrict__ smax_e,
                       float* __restrict__ sumex, unsigned* __restrict__ gmax_e,
                       float* __restrict__ degfc, int* __restrict__ counters,
                       int n, int kcap) {
  int i = blockIdx.x * blockDim.x + threadIdx.x;
  if (i < n) {
    deg[i] = 1.0f;                       // self-loop
    agg[i] = 0.0f;
    xw[i]  = x[2 * i] * gcn_w[0] + x[2 * i + 1] * gcn_w[1];
  }
  if (i < NG) { smax_e[i] = encf(-INFINITY); sumex[i] = 0.0f; }
  if (i < NG * 3 * GW) gmax_e[i] = encf(NEGV);
  if (i < kcap) degfc[i] = 0.0f;
  if (i == 0) { counters[0] = 0; counters[1] = 0; }
}

__global__ void k_deg(const int* __restrict__ dst, float* __restrict__ deg, int ne) {
  int e = blockIdx.x * blockDim.x + threadIdx.x;
  if (e < ne) atomicAdd(&deg[dst[e]], 1.0f);
}

__global__ void k_dinv(float* __restrict__ deg, int n) {
  int i = blockIdx.x * blockDim.x + threadIdx.x;
  if (i < n) deg[i] = 1.0f / sqrtf(deg[i]);   // deg -> dinv in place
}

__global__ void k_aggk(const int* __restrict__ src, const int* __restrict__ dst,
                       const float* __restrict__ xw, const float* __restrict__ dinv,
                       float* __restrict__ agg, int ne) {
  int e = blockIdx.x * blockDim.x + threadIdx.x;
  if (e < ne) {
    int s = src[e], d = dst[e];
    atomicAdd(&agg[d], xw[s] * dinv[s] * dinv[d]);
  }
}

__global__ void k_sraw(const float* __restrict__ agg, const float* __restrict__ xw,
                       const float* __restrict__ dinv, const int* __restrict__ batch,
                       const float* __restrict__ gcn_b, const float* __restrict__ topk_w,
                       float* __restrict__ s_raw, unsigned* __restrict__ smax_e, int n) {
  __shared__ unsigned ls[NG];
  int t = threadIdx.x;
  if (t < NG) ls[t] = encf(-INFINITY);
  __syncthreads();
  int i = blockIdx.x * blockDim.x + t;
  if (i < n) {
    float di   = dinv[i];
    float attn = agg[i] + xw[i] * di * di + gcn_b[0];
    float s    = attn * topk_w[0];
    s_raw[i]   = s;
    atomicMax(&ls[batch[i]], encf(s));
  }
  __syncthreads();
  if (t < NG) atomicMax(&smax_e[t], ls[t]);
}

__global__ void k_ex(const float* __restrict__ s_raw, const int* __restrict__ batch,
                     const unsigned* __restrict__ smax_e, float* __restrict__ ex,
                     float* __restrict__ sumex, int n) {
  __shared__ float lsum[NG];
  int t = threadIdx.x;
  if (t < NG) lsum[t] = 0.0f;
  __syncthreads();
  int i = blockIdx.x * blockDim.x + t;
  if (i < n) {
    int b = batch[i];
    float e = expf(s_raw[i] - decf(smax_e[b]));
    ex[i] = e;
    atomicAdd(&lsum[b], e);
  }
  __syncthreads();
  if (t < NG && lsum[t] != 0.0f) atomicAdd(&sumex[t], lsum[t]);
}

__global__ void k_compact_n(const float* __restrict__ ex, const float* __restrict__ sumex,
                            const int* __restrict__ batch, const float* __restrict__ x,
                            int* __restrict__ kmap, int* __restrict__ kbatch,
                            float* __restrict__ hk, float* __restrict__ tx0,
                            int* __restrict__ counters, int n, int kcap) {
  int i = blockIdx.x * blockDim.x + threadIdx.x;
  if (i >= n) return;
  int b = batch[i];
  float se    = sumex[b];
  float score = ex[i] / se;
  float thr   = fminf(1.0f / se - TOLK, MIN_SCORE);  // max(score) == fl(1/se) exactly
  int m = -1;
  if (score > thr) {
    int idx = atomicAdd(&counters[0], 1);
    if (idx < kcap) {
      m = idx;
      kbatch[idx]      = b;
      hk[2 * idx]      = x[2 * i] * score;
      hk[2 * idx + 1]  = x[2 * i + 1] * score;
      tx0[2 * idx]     = 0.0f;
      tx0[2 * idx + 1] = 0.0f;
    }
  }
  kmap[i] = m;
}

__global__ void k_compact_e(const int* __restrict__ src, const int* __restrict__ dst,
                            const int* __restrict__ kmap, int* __restrict__ eks,
                            int* __restrict__ ekd, float* __restrict__ degfc,
                            int* __restrict__ counters, int ne, int ecap) {
  int e = blockIdx.x * blockDim.x + threadIdx.x;
  if (e >= ne) return;
  int ks = kmap[src[e]];
  if (ks < 0) return;
  int kd = kmap[dst[e]];
  if (kd < 0) return;
  int j = atomicAdd(&counters[1], 1);
  if (j < ecap) {
    eks[j] = ks;
    ekd[j] = kd;
    atomicAdd(&degfc[kd], 1.0f);
  }
}

template <int LOGD>
__global__ void k_edge_agg(const int* __restrict__ eks, const int* __restrict__ ekd,
                           const float* __restrict__ degfc, const float* __restrict__ h_in,
                           float* __restrict__ tx, const int* __restrict__ counters, int ecap) {
  int S = counters[1];
  if (S > ecap) S = ecap;
  const int D = 1 << LOGD;
  long total = (long)S << LOGD;
  long stride = (long)gridDim.x * blockDim.x;
  for (long idx = (long)blockIdx.x * blockDim.x + threadIdx.x; idx < total; idx += stride) {
    int e = (int)(idx >> LOGD);
    int c = (int)(idx & (D - 1));
    int ks = eks[e], kd = ekd[e];
    float dfs = degfc[ks], dfd = degfc[kd];
    float a  = dfs > 0.0f ? 1.0f / sqrtf(dfs) : 0.0f;
    float bb = dfd > 0.0f ? 1.0f / sqrtf(dfd) : 0.0f;
    float nf = a * bb;
    atomicAdd(&tx[kd * D + c], -h_in[ks * D + c] * nf);
  }
}

// out[j] = bn(elu(h@w0 + tx@w1 + b)); also per-graph atomic max; optionally zero tx_next.
template <int DIN>
__global__ void k_mm(const float* __restrict__ h_in, const float* __restrict__ tx_in,
                     const float* __restrict__ w0, const float* __restrict__ w1,
                     const float* __restrict__ bias, const float* __restrict__ bn_g,
                     const float* __restrict__ bn_b, const float* __restrict__ bn_m,
                     const float* __restrict__ bn_v, int goff,
                     const int* __restrict__ kbatch, const int* __restrict__ counters,
                     int kcap, float* __restrict__ h_out, unsigned* __restrict__ gmax_e,
                     float* __restrict__ tx_next) {
  __shared__ float lh[DIN];
  __shared__ float lt[DIN];
  int K = counters[0];
  if (K > kcap) K = kcap;
  int j = threadIdx.x;  // 0..GW-1
  float scale = bn_g[j] * (1.0f / sqrtf(bn_v[j] + EPSBN));
  float mean = bn_m[j], beta = bn_b[j], bj = bias[j];
  for (int i = blockIdx.x; i < K; i += gridDim.x) {
    if (j < DIN) { lh[j] = h_in[i * DIN + j]; lt[j] = tx_in[i * DIN + j]; }
    __syncthreads();
    float acc = bj;
    #pragma unroll 8
    for (int k = 0; k < DIN; ++k)
      acc += lh[k] * w0[k * GW + j] + lt[k] * w1[k * GW + j];
    float v = eluf(acc);
    v = (v - mean) * scale + beta;
    h_out[i * GW + j] = v;
    atomicMax(&gmax_e[kbatch[i] * (3 * GW) + goff + j], encf(v));
    if (tx_next) tx_next[i * GW + j] = 0.0f;
    __syncthreads();
  }
}

__global__ void k_final(const unsigned* __restrict__ gmax_e,
                        const float* __restrict__ l0w, const float* __restrict__ l0b,
                        const float* __restrict__ l1w, const float* __restrict__ l1b,
                        const float* __restrict__ lfw, const float* __restrict__ lfb,
                        float* __restrict__ out) {
  __shared__ float gv[3 * GW];
  __shared__ float t0[32];
  __shared__ float t1[8];
  __shared__ float lg[3];
  int g = blockIdx.x;
  int t = threadIdx.x;  // 64 threads
  for (int k = t; k < 3 * GW; k += blockDim.x) gv[k] = decf(gmax_e[g * 3 * GW + k]);
  __syncthreads();
  if (t < 32) {
    float acc = l0b[t];
    for (int k = 0; k < 3 * GW; ++k) acc += gv[k] * l0w[k * 32 + t];
    t0[t] = eluf(acc);
  }
  __syncthreads();
  if (t < 8) {
    float acc = l1b[t];
    for (int k = 0; k < 32; ++k) acc += t0[k] * l1w[k * 8 + t];
    t1[t] = eluf(acc);
  }
  __syncthreads();
  if (t < 3) {
    float acc = lfb[t];
    for (int k = 0; k < 8; ++k) acc += t1[k] * lfw[k * 3 + t];
    lg[t] = acc;
  }
  __syncthreads();
  if (t == 0) {
    float m = fmaxf(lg[0], fmaxf(lg[1], lg[2]));
    float s = expf(lg[0] - m) + expf(lg[1] - m) + expf(lg[2] - m);
    float ls = m + logf(s);
    out[g * 3 + 0] = lg[0] - ls;
    out[g * 3 + 1] = lg[1] - ls;
    out[g * 3 + 2] = lg[2] - ls;
  }
}

// ---------- launcher ----------
extern "C" void kernel_launch(void* const* d_in, const int* in_sizes, int n_in,
                              void* d_out, int out_size, void* d_ws, size_t ws_size,
                              hipStream_t stream) {
  const float* x      = (const float*)d_in[0];
  const int*   ei     = (const int*)d_in[1];
  const int*   batch  = (const int*)d_in[2];
  const float* gcn_w  = (const float*)d_in[3];
  const float* gcn_b  = (const float*)d_in[4];
  const float* topk_w = (const float*)d_in[5];
  const float* c0w0 = (const float*)d_in[6],  *c0w1 = (const float*)d_in[7],  *c0b = (const float*)d_in[8];
  const float* c1w0 = (const float*)d_in[9],  *c1w1 = (const float*)d_in[10], *c1b = (const float*)d_in[11];
  const float* c2w0 = (const float*)d_in[12], *c2w1 = (const float*)d_in[13], *c2b = (const float*)d_in[14];
  const float* bng = (const float*)d_in[15], *bnb = (const float*)d_in[16];
  const float* bnm = (const float*)d_in[17], *bnv = (const float*)d_in[18];
  const float* l0w = (const float*)d_in[19], *l0b = (const float*)d_in[20];
  const float* l1w = (const float*)d_in[21], *l1b = (const float*)d_in[22];
  const float* lfw = (const float*)d_in[23], *lfb = (const float*)d_in[24];
  float* out = (float*)d_out;

  const int n  = in_sizes[2];       // N nodes (batch_index length)
  const int ne = in_sizes[1] / 2;   // E edges
  const int* src = ei;
  const int* dst = ei + ne;

  // --- workspace sizing: shrink caps until we fit ---
  int kcap = 16384, ecap = 262144;
  auto tneed = [&](size_t kc, size_t ec) -> size_t {
    auto al = [](size_t b) { return (b + 255) & ~(size_t)255; };
    size_t t = 0;
    t += al((size_t)n * 4) * 6;               // xw, deg, agg, s_raw, ex, kmap
    t += al(NG * 4) * 2;                      // smax_e, sumex
    t += al(NG * 3 * GW * 4);                 // gmax_e
    t += al(8);                               // counters
    t += al(kc * 4) * 2;                      // kbatch, degfc
    t += al(kc * 8) * 2;                      // hk, tx0
    t += al(kc * GW * 4) * 3;                 // hA, hB, tx
    t += al(ec * 4) * 2;                      // eks, ekd
    return t;
  };
  while (kcap > 128 && tneed(kcap, ecap) > ws_size) { kcap >>= 1; ecap >>= 1; }

  char* base = (char*)d_ws;
  size_t off = 0;
  auto A = [&](size_t bytes) -> void* {
    void* r = (void*)(base + off);
    off += (bytes + 255) & ~(size_t)255;
    return r;
  };
  float*    xw     = (float*)A((size_t)n * 4);
  float*    deg    = (float*)A((size_t)n * 4);   // becomes dinv in place
  float*    agg    = (float*)A((size_t)n * 4);
  float*    s_raw  = (float*)A((size_t)n * 4);
  float*    ex     = (float*)A((size_t)n * 4);
  int*      kmap   = (int*)A((size_t)n * 4);
  unsigned* smax_e = (unsigned*)A(NG * 4);
  float*    sumex  = (float*)A(NG * 4);
  unsigned* gmax_e = (unsigned*)A(NG * 3 * GW * 4);
  int*      counters = (int*)A(8);
  int*      kbatch = (int*)A((size_t)kcap * 4);
  float*    degfc  = (float*)A((size_t)kcap * 4);
  float*    hk     = (float*)A((size_t)kcap * 8);
  float*    tx0    = (float*)A((size_t)kcap * 8);
  float*    hA     = (float*)A((size_t)kcap * GW * 4);
  float*    hB     = (float*)A((size_t)kcap * GW * 4);
  float*    tx     = (float*)A((size_t)kcap * GW * 4);
  int*      eks    = (int*)A((size_t)ecap * 4);
  int*      ekd    = (int*)A((size_t)ecap * 4);

  const int nbN = (n + 255) / 256;
  const int nbE = (ne + 255) / 256;

  k_init<<<nbN, 256, 0, stream>>>(x, gcn_w, deg, agg, xw, smax_e, sumex, gmax_e,
                                  degfc, counters, n, kcap);
  k_deg<<<nbE, 256, 0, stream>>>(dst, deg, ne);
  k_dinv<<<nbN, 256, 0, stream>>>(deg, n);
  k_aggk<<<nbE, 256, 0, stream>>>(src, dst, xw, deg, agg, ne);
  k_sraw<<<nbN, 256, 0, stream>>>(agg, xw, deg, batch, gcn_b, topk_w, s_raw, smax_e, n);
  k_ex<<<nbN, 256, 0, stream>>>(s_raw, batch, smax_e, ex, sumex, n);
  k_compact_n<<<nbN, 256, 0, stream>>>(ex, sumex, batch, x, kmap, kbatch, hk, tx0,
                                       counters, n, kcap);
  k_compact_e<<<nbE, 256, 0, stream>>>(src, dst, kmap, eks, ekd, degfc, counters, ne, ecap);

  // Layer 0 (din=2): edge agg into tx0, then MM -> hA (zeroes tx for layer 1)
  k_edge_agg<1><<<512, 256, 0, stream>>>(eks, ekd, degfc, hk, tx0, counters, ecap);
  k_mm<2><<<1024, GW, 0, stream>>>(hk, tx0, c0w0, c0w1, c0b,
                                   bng + 0 * GW, bnb + 0 * GW, bnm + 0 * GW, bnv + 0 * GW,
                                   0 * GW, kbatch, counters, kcap, hA, gmax_e, tx);
  // Layer 1: edge agg into tx, MM -> hB (re-zeroes tx for layer 2)
  k_edge_agg<7><<<512, 256, 0, stream>>>(eks, ekd, degfc, hA, tx, counters, ecap);
  k_mm<GW><<<1024, GW, 0, stream>>>(hA, tx, c1w0, c1w1, c1b,
                                    bng + 1 * GW, bnb + 1 * GW, bnm + 1 * GW, bnv + 1 * GW,
                                    1 * GW, kbatch, counters, kcap, hB, gmax_e, tx);
  // Layer 2: edge agg into tx, MM -> hA (no zeroing needed)
  k_edge_agg<7><<<512, 256, 0, stream>>>(eks, ekd, degfc, hB, tx, counters, ecap);
  k_mm<GW><<<1024, GW, 0, stream>>>(hB, tx, c2w0, c2w1, c2b,
                                    bng + 2 * GW, bnb + 2 * GW, bnm + 2 * GW, bnv + 2 * GW,
                                    2 * GW, kbatch, counters, kcap, hA, gmax_e, nullptr);

  k_final<<<NG, 64, 0, stream>>>(gmax_e, l0w, l0b, l1w, l1b, lfw, lfb, out);
}

// Round 2
// 146.584 us; speedup vs baseline: 1.5682x; 1.5682x over previous
//
#include <hip/hip_runtime.h>
#include <math.h>

#define NG 16
#define GW 128
#define NEGV -1.0e9f
#define EPSBN 1e-5f
#define MIN_SCORE 0.1f
#define TOLK 1e-7f
#define NBIN 1024
#define NPBMAX 256
#define EPT 32           // edges per thread in scatter

// ---------- helpers ----------
__device__ __forceinline__ unsigned encf(float f) {
  unsigned u = __float_as_uint(f);
  return (u & 0x80000000u) ? ~u : (u | 0x80000000u);
}
__device__ __forceinline__ float decf(unsigned u) {
  unsigned b = (u & 0x80000000u) ? (u & 0x7fffffffu) : ~u;
  return __uint_as_float(b);
}
__device__ __forceinline__ float eluf(float v) { return v > 0.0f ? v : expm1f(v); }

// ---------- kernels ----------
__global__ void k_init(const float* __restrict__ x, const float* __restrict__ gcn_w,
                       float* __restrict__ xw, unsigned* __restrict__ smax_e,
                       float* __restrict__ sumex, unsigned* __restrict__ gmax_e,
                       float* __restrict__ degfc, int* __restrict__ counters,
                       int* __restrict__ hist, int n, int kcap) {
  int i = blockIdx.x * blockDim.x + threadIdx.x;
  if (i < n) xw[i] = x[2 * i] * gcn_w[0] + x[2 * i + 1] * gcn_w[1];
  if (i < NG) { smax_e[i] = encf(-INFINITY); sumex[i] = 0.0f; }
  if (i < NG * 3 * GW) gmax_e[i] = encf(NEGV);
  if (i < kcap) degfc[i] = 0.0f;
  if (i < NBIN) hist[i] = 0;
  if (i == 0) { counters[0] = 0; counters[1] = 0; }
}

__global__ void k_hist(const int* __restrict__ dst, int ne, int shift,
                       int* __restrict__ hist) {
  __shared__ int lh[NBIN];
  for (int b = threadIdx.x; b < NBIN; b += blockDim.x) lh[b] = 0;
  __syncthreads();
  for (int e = blockIdx.x * blockDim.x + threadIdx.x; e < ne;
       e += gridDim.x * blockDim.x)
    atomicAdd(&lh[dst[e] >> shift], 1);
  __syncthreads();
  for (int b = threadIdx.x; b < NBIN; b += blockDim.x)
    if (lh[b]) atomicAdd(&hist[b], lh[b]);
}

__global__ void k_prefix(const int* __restrict__ hist, int* __restrict__ base,
                         int* __restrict__ cursor) {
  __shared__ int s[NBIN];
  int t = threadIdx.x;
  s[t] = hist[t];
  __syncthreads();
  for (int o = 1; o < NBIN; o <<= 1) {
    int v = (t >= o) ? s[t - o] : 0;
    __syncthreads();
    s[t] += v;
    __syncthreads();
  }
  int ex = s[t] - hist[t];
  base[t] = ex;
  cursor[t] = ex;
}

// sort edges by dst-bucket; payload = (dst_local<<24) | src  (needs n < 2^24, NPB<=256)
__global__ void k_scatter(const int* __restrict__ src, const int* __restrict__ dst,
                          int ne, int shift, int* __restrict__ cursor,
                          unsigned* __restrict__ sorted) {
  __shared__ int lh[NBIN];
  __shared__ int gb[NBIN];
  int t = threadIdx.x;
  for (int b = t; b < NBIN; b += blockDim.x) lh[b] = 0;
  __syncthreads();
  int ebase = blockIdx.x * (1024 * EPT);
  int rank[EPT];
  #pragma unroll
  for (int k = 0; k < EPT; ++k) {
    int e = ebase + k * 1024 + t;
    rank[k] = 0;
    if (e < ne) rank[k] = atomicAdd(&lh[dst[e] >> shift], 1);
  }
  __syncthreads();
  for (int b = t; b < NBIN; b += blockDim.x) {
    gb[b] = 0;
    if (lh[b]) gb[b] = atomicAdd(&cursor[b], lh[b]);
  }
  __syncthreads();
  #pragma unroll
  for (int k = 0; k < EPT; ++k) {
    int e = ebase + k * 1024 + t;
    if (e < ne) {
      int d = dst[e];
      int bin = d >> shift;
      int dl = d - (bin << shift);
      sorted[gb[bin] + rank[k]] = ((unsigned)dl << 24) | (unsigned)src[e];
    }
  }
}

// per-bucket: deg count (LDS) -> dinv + y = xw*dinv
__global__ void k_c1(const unsigned* __restrict__ sorted, const int* __restrict__ base,
                     const int* __restrict__ hist, const float* __restrict__ xw,
                     float* __restrict__ dinv, float* __restrict__ y,
                     int n, int shift) {
  __shared__ int ldeg[NPBMAX];
  int b = blockIdx.x;
  int off = b << shift;
  if (off >= n) return;
  int npb = 1 << shift;
  int t = threadIdx.x;
  for (int j = t; j < npb; j += blockDim.x) ldeg[j] = 0;
  __syncthreads();
  int s0 = base[b], cnt = hist[b];
  for (int i = t; i < cnt; i += blockDim.x)
    atomicAdd(&ldeg[sorted[s0 + i] >> 24], 1);
  __syncthreads();
  for (int j = t; j < npb; j += blockDim.x) {
    int g = off + j;
    if (g < n) {
      float dv = rsqrtf((float)(ldeg[j] + 1));   // +1 self loop
      dinv[g] = dv;
      y[g] = xw[g] * dv;
    }
  }
}

// per-bucket: t[d] = sum y[src] (LDS fp); then attn -> s_raw + per-graph max
__global__ void k_c2(const unsigned* __restrict__ sorted, const int* __restrict__ base,
                     const int* __restrict__ hist, const float* __restrict__ y,
                     const float* __restrict__ xw, const float* __restrict__ dinv,
                     const int* __restrict__ batch, const float* __restrict__ gcn_b,
                     const float* __restrict__ topk_w, float* __restrict__ s_raw,
                     unsigned* __restrict__ smax_e, int n, int shift) {
  __shared__ float lt[NPBMAX];
  __shared__ unsigned ls[NG];
  int b = blockIdx.x;
  int off = b << shift;
  if (off >= n) return;
  int npb = 1 << shift;
  int t = threadIdx.x;
  for (int j = t; j < npb; j += blockDim.x) lt[j] = 0.0f;
  if (t < NG) ls[t] = encf(-INFINITY);
  __syncthreads();
  int s0 = base[b], cnt = hist[b];
  for (int i = t; i < cnt; i += blockDim.x) {
    unsigned p = sorted[s0 + i];
    atomicAdd(&lt[p >> 24], y[p & 0xFFFFFFu]);
  }
  __syncthreads();
  float gb_ = gcn_b[0], tw = topk_w[0];
  for (int j = t; j < npb; j += blockDim.x) {
    int g = off + j;
    if (g < n) {
      float dv = dinv[g];
      float attn = dv * lt[j] + xw[g] * dv * dv + gb_;
      float s = attn * tw;
      s_raw[g] = s;
      atomicMax(&ls[batch[g]], encf(s));
    }
  }
  __syncthreads();
  if (t < NG && ls[t] != encf(-INFINITY)) atomicMax(&smax_e[t], ls[t]);
}

__global__ void k_ex(const float* __restrict__ s_raw, const int* __restrict__ batch,
                     const unsigned* __restrict__ smax_e, float* __restrict__ ex,
                     float* __restrict__ sumex, int n) {
  __shared__ float lsum[NG];
  int t = threadIdx.x;
  if (t < NG) lsum[t] = 0.0f;
  __syncthreads();
  int i = blockIdx.x * blockDim.x + t;
  if (i < n) {
    int b = batch[i];
    float e = expf(s_raw[i] - decf(smax_e[b]));
    ex[i] = e;
    atomicAdd(&lsum[b], e);
  }
  __syncthreads();
  if (t < NG && lsum[t] != 0.0f) atomicAdd(&sumex[t], lsum[t]);
}

__global__ void k_compact_n(const float* __restrict__ ex, const float* __restrict__ sumex,
                            const int* __restrict__ batch, const float* __restrict__ x,
                            int* __restrict__ kmap, int* __restrict__ kbatch,
                            float* __restrict__ hk, float* __restrict__ tx0,
                            int* __restrict__ counters, int n, int kcap) {
  int i = blockIdx.x * blockDim.x + threadIdx.x;
  if (i >= n) return;
  int b = batch[i];
  float se = sumex[b];
  float score = ex[i] / se;
  float thr = fminf(1.0f / se - TOLK, MIN_SCORE);  // max(score) == fl(1/se) exactly
  int m = -1;
  if (score > thr) {
    int idx = atomicAdd(&counters[0], 1);
    if (idx < kcap) {
      m = idx;
      kbatch[idx] = b;
      hk[2 * idx] = x[2 * i] * score;
      hk[2 * idx + 1] = x[2 * i + 1] * score;
      tx0[2 * idx] = 0.0f;
      tx0[2 * idx + 1] = 0.0f;
    }
  }
  kmap[i] = m;
}

__global__ void k_compact_e(const int* __restrict__ src, const int* __restrict__ dst,
                            const int* __restrict__ kmap, int* __restrict__ eks,
                            int* __restrict__ ekd, float* __restrict__ degfc,
                            int* __restrict__ counters, int ne, int ecap) {
  int e = blockIdx.x * blockDim.x + threadIdx.x;
  if (e >= ne) return;
  int ks = kmap[src[e]];
  if (ks < 0) return;
  int kd = kmap[dst[e]];
  if (kd < 0) return;
  int j = atomicAdd(&counters[1], 1);
  if (j < ecap) {
    eks[j] = ks;
    ekd[j] = kd;
    atomicAdd(&degfc[kd], 1.0f);
  }
}

template <int LOGD>
__global__ void k_edge_agg(const int* __restrict__ eks, const int* __restrict__ ekd,
                           const float* __restrict__ degfc, const float* __restrict__ h_in,
                           float* __restrict__ tx, const int* __restrict__ counters, int ecap) {
  int S = counters[1];
  if (S > ecap) S = ecap;
  const int D = 1 << LOGD;
  long total = (long)S << LOGD;
  long stride = (long)gridDim.x * blockDim.x;
  for (long idx = (long)blockIdx.x * blockDim.x + threadIdx.x; idx < total; idx += stride) {
    int e = (int)(idx >> LOGD);
    int c = (int)(idx & (D - 1));
    int ks = eks[e], kd = ekd[e];
    float dfs = degfc[ks], dfd = degfc[kd];
    float a = dfs > 0.0f ? 1.0f / sqrtf(dfs) : 0.0f;
    float bb = dfd > 0.0f ? 1.0f / sqrtf(dfd) : 0.0f;
    float nf = a * bb;
    atomicAdd(&tx[kd * D + c], -h_in[ks * D + c] * nf);
  }
}

template <int DIN>
__global__ void k_mm(const float* __restrict__ h_in, const float* __restrict__ tx_in,
                     const float* __restrict__ w0, const float* __restrict__ w1,
                     const float* __restrict__ bias, const float* __restrict__ bn_g,
                     const float* __restrict__ bn_b, const float* __restrict__ bn_m,
                     const float* __restrict__ bn_v, int goff,
                     const int* __restrict__ kbatch, const int* __restrict__ counters,
                     int kcap, float* __restrict__ h_out, unsigned* __restrict__ gmax_e,
                     float* __restrict__ tx_next) {
  __shared__ float lh[DIN];
  __shared__ float lt[DIN];
  int K = counters[0];
  if (K > kcap) K = kcap;
  int j = threadIdx.x;  // 0..GW-1
  float scale = bn_g[j] * (1.0f / sqrtf(bn_v[j] + EPSBN));
  float mean = bn_m[j], beta = bn_b[j], bj = bias[j];
  for (int i = blockIdx.x; i < K; i += gridDim.x) {
    if (j < DIN) { lh[j] = h_in[i * DIN + j]; lt[j] = tx_in[i * DIN + j]; }
    __syncthreads();
    float acc = bj;
    #pragma unroll 8
    for (int k = 0; k < DIN; ++k)
      acc += lh[k] * w0[k * GW + j] + lt[k] * w1[k * GW + j];
    float v = eluf(acc);
    v = (v - mean) * scale + beta;
    h_out[i * GW + j] = v;
    atomicMax(&gmax_e[kbatch[i] * (3 * GW) + goff + j], encf(v));
    if (tx_next) tx_next[i * GW + j] = 0.0f;
    __syncthreads();
  }
}

__global__ void k_final(const unsigned* __restrict__ gmax_e,
                        const float* __restrict__ l0w, const float* __restrict__ l0b,
                        const float* __restrict__ l1w, const float* __restrict__ l1b,
                        const float* __restrict__ lfw, const float* __restrict__ lfb,
                        float* __restrict__ out) {
  __shared__ float gv[3 * GW];
  __shared__ float t0[32];
  __shared__ float t1[8];
  __shared__ float lg[3];
  int g = blockIdx.x;
  int t = threadIdx.x;  // 64 threads
  for (int k = t; k < 3 * GW; k += blockDim.x) gv[k] = decf(gmax_e[g * 3 * GW + k]);
  __syncthreads();
  if (t < 32) {
    float acc = l0b[t];
    for (int k = 0; k < 3 * GW; ++k) acc += gv[k] * l0w[k * 32 + t];
    t0[t] = eluf(acc);
  }
  __syncthreads();
  if (t < 8) {
    float acc = l1b[t];
    for (int k = 0; k < 32; ++k) acc += t0[k] * l1w[k * 8 + t];
    t1[t] = eluf(acc);
  }
  __syncthreads();
  if (t < 3) {
    float acc = lfb[t];
    for (int k = 0; k < 8; ++k) acc += t1[k] * lfw[k * 3 + t];
    lg[t] = acc;
  }
  __syncthreads();
  if (t == 0) {
    float m = fmaxf(lg[0], fmaxf(lg[1], lg[2]));
    float s = expf(lg[0] - m) + expf(lg[1] - m) + expf(lg[2] - m);
    float ls = m + logf(s);
    out[g * 3 + 0] = lg[0] - ls;
    out[g * 3 + 1] = lg[1] - ls;
    out[g * 3 + 2] = lg[2] - ls;
  }
}

// ---------- launcher ----------
extern "C" void kernel_launch(void* const* d_in, const int* in_sizes, int n_in,
                              void* d_out, int out_size, void* d_ws, size_t ws_size,
                              hipStream_t stream) {
  const float* x      = (const float*)d_in[0];
  const int*   ei     = (const int*)d_in[1];
  const int*   batch  = (const int*)d_in[2];
  const float* gcn_w  = (const float*)d_in[3];
  const float* gcn_b  = (const float*)d_in[4];
  const float* topk_w = (const float*)d_in[5];
  const float* c0w0 = (const float*)d_in[6],  *c0w1 = (const float*)d_in[7],  *c0b = (const float*)d_in[8];
  const float* c1w0 = (const float*)d_in[9],  *c1w1 = (const float*)d_in[10], *c1b = (const float*)d_in[11];
  const float* c2w0 = (const float*)d_in[12], *c2w1 = (const float*)d_in[13], *c2b = (const float*)d_in[14];
  const float* bng = (const float*)d_in[15], *bnb = (const float*)d_in[16];
  const float* bnm = (const float*)d_in[17], *bnv = (const float*)d_in[18];
  const float* l0w = (const float*)d_in[19], *l0b = (const float*)d_in[20];
  const float* l1w = (const float*)d_in[21], *l1b = (const float*)d_in[22];
  const float* lfw = (const float*)d_in[23], *lfb = (const float*)d_in[24];
  float* out = (float*)d_out;

  const int n  = in_sizes[2];       // N nodes
  const int ne = in_sizes[1] / 2;   // E edges
  const int* src = ei;
  const int* dst = ei + ne;

  // bucket shift: smallest with (n-1)>>shift < NBIN; NPB = 1<<shift (<= NPBMAX)
  int shift = 0;
  while (((n - 1) >> shift) >= NBIN) shift++;
  if (shift > 8) shift = 8;  // supports n <= 262144

  int kcap = 4096, ecap = 65536;
  auto tneed = [&](size_t kc, size_t ec) -> size_t {
    auto al = [](size_t b) { return (b + 255) & ~(size_t)255; };
    size_t t = 0;
    t += al((size_t)n * 4) * 6;               // xw, dinv, y, s_raw, ex, kmap
    t += al((size_t)ne * 4);                  // sorted
    t += al(NBIN * 4) * 3;                    // hist, base, cursor
    t += al(NG * 4) * 2;                      // smax_e, sumex
    t += al(NG * 3 * GW * 4);                 // gmax_e
    t += al(8);                               // counters
    t += al(kc * 4) * 2;                      // kbatch, degfc
    t += al(kc * 8) * 2;                      // hk, tx0
    t += al(kc * GW * 4) * 3;                 // hA, hB, tx
    t += al(ec * 4) * 2;                      // eks, ekd
    return t;
  };
  while (kcap > 128 && tneed(kcap, ecap) > ws_size) { kcap >>= 1; ecap >>= 1; }

  char* bp = (char*)d_ws;
  size_t off = 0;
  auto A = [&](size_t bytes) -> void* {
    void* r = (void*)(bp + off);
    off += (bytes + 255) & ~(size_t)255;
    return r;
  };
  float*    xw     = (float*)A((size_t)n * 4);
  float*    dinv   = (float*)A((size_t)n * 4);
  float*    y      = (float*)A((size_t)n * 4);
  float*    s_raw  = (float*)A((size_t)n * 4);
  float*    ex     = (float*)A((size_t)n * 4);
  int*      kmap   = (int*)A((size_t)n * 4);
  unsigned* sorted = (unsigned*)A((size_t)ne * 4);
  int*      hist   = (int*)A(NBIN * 4);
  int*      binb   = (int*)A(NBIN * 4);
  int*      cursor = (int*)A(NBIN * 4);
  unsigned* smax_e = (unsigned*)A(NG * 4);
  float*    sumex  = (float*)A(NG * 4);
  unsigned* gmax_e = (unsigned*)A(NG * 3 * GW * 4);
  int*      counters = (int*)A(8);
  int*      kbatch = (int*)A((size_t)kcap * 4);
  float*    degfc  = (float*)A((size_t)kcap * 4);
  float*    hk     = (float*)A((size_t)kcap * 8);
  float*    tx0    = (float*)A((size_t)kcap * 8);
  float*    hA     = (float*)A((size_t)kcap * GW * 4);
  float*    hB     = (float*)A((size_t)kcap * GW * 4);
  float*    tx     = (float*)A((size_t)kcap * GW * 4);
  int*      eks    = (int*)A((size_t)ecap * 4);
  int*      ekd    = (int*)A((size_t)ecap * 4);

  const int nbN = (n + 255) / 256;
  const int nbE = (ne + 255) / 256;
  const int nbS = (ne + 1024 * EPT - 1) / (1024 * EPT);

  k_init<<<nbN, 256, 0, stream>>>(x, gcn_w, xw, smax_e, sumex, gmax_e, degfc,
                                  counters, hist, n, kcap);
  k_hist<<<64, 1024, 0, stream>>>(dst, ne, shift, hist);
  k_prefix<<<1, NBIN, 0, stream>>>(hist, binb, cursor);
  k_scatter<<<nbS, 1024, 0, stream>>>(src, dst, ne, shift, cursor, sorted);
  k_c1<<<NBIN, 256, 0, stream>>>(sorted, binb, hist, xw, dinv, y, n, shift);
  k_c2<<<NBIN, 256, 0, stream>>>(sorted, binb, hist, y, xw, dinv, batch, gcn_b,
                                 topk_w, s_raw, smax_e, n, shift);
  k_ex<<<nbN, 256, 0, stream>>>(s_raw, batch, smax_e, ex, sumex, n);
  k_compact_n<<<nbN, 256, 0, stream>>>(ex, sumex, batch, x, kmap, kbatch, hk, tx0,
                                       counters, n, kcap);
  k_compact_e<<<nbE, 256, 0, stream>>>(src, dst, kmap, eks, ekd, degfc, counters, ne, ecap);

  k_edge_agg<1><<<64, 256, 0, stream>>>(eks, ekd, degfc, hk, tx0, counters, ecap);
  k_mm<2><<<128, GW, 0, stream>>>(hk, tx0, c0w0, c0w1, c0b,
                                  bng + 0 * GW, bnb + 0 * GW, bnm + 0 * GW, bnv + 0 * GW,
                                  0 * GW, kbatch, counters, kcap, hA, gmax_e, tx);
  k_edge_agg<7><<<64, 256, 0, stream>>>(eks, ekd, degfc, hA, tx, counters, ecap);
  k_mm<GW><<<128, GW, 0, stream>>>(hA, tx, c1w0, c1w1, c1b,
                                   bng + 1 * GW, bnb + 1 * GW, bnm + 1 * GW, bnv + 1 * GW,
                                   1 * GW, kbatch, counters, kcap, hB, gmax_e, tx);
  k_edge_agg<7><<<64, 256, 0, stream>>>(eks, ekd, degfc, hB, tx, counters, ecap);
  k_mm<GW><<<128, GW, 0, stream>>>(hB, tx, c2w0, c2w1, c2b,
                                   bng + 2 * GW, bnb + 2 * GW, bnm + 2 * GW, bnv + 2 * GW,
                                   2 * GW, kbatch, counters, kcap, hA, gmax_e, nullptr);

  k_final<<<NG, 64, 0, stream>>>(gmax_e, l0w, l0b, l1w, l1b, lfw, lfb, out);
}